// Round 7
// baseline (1084.353 us; speedup 1.0000x reference)
//
#include <hip/hip_runtime.h>

namespace {

constexpr int T = 64;
constexpr int S = 512;
constexpr int B = 32;
constexpr int DEPTH = 4;   // LDS ring depth; steady-state wait = vmcnt(16*(DEPTH-1)) = 48 (hw max 63)

#define WAIT_VM48() asm volatile("s_waitcnt vmcnt(48)" ::: "memory")
#define WAIT_VM0()  asm volatile("s_waitcnt vmcnt(0)" ::: "memory")
#define WAIT_LGKM() asm volatile("s_waitcnt lgkmcnt(0)" ::: "memory")

__device__ __forceinline__ void load16(const float* g, float* l) {
  // async global->LDS: global addr is per-lane, LDS dst = wave-uniform base + lane*16
  __builtin_amdgcn_global_load_lds(
      (const __attribute__((address_space(1))) void*)g,
      (__attribute__((address_space(3))) void*)l, 16, 0, 0);
}

// order-preserving float<->uint (monotone for all non-NaN)
__device__ __forceinline__ unsigned int f2s(float f) {
  unsigned int u = __float_as_uint(f);
  return u ^ (unsigned int)(((int)u >> 31) | 0x80000000u);
}
__device__ __forceinline__ float s2f(unsigned int u) {
  u ^= (u & 0x80000000u) ? 0x80000000u : 0xFFFFFFFFu;
  return __uint_as_float(u);
}

// butterfly max of packed u64 across lanes differing in bit-mask xm (intra-wave, no barrier)
__device__ __forceinline__ unsigned long long u64max_x(unsigned long long v, int xm) {
  unsigned int hi = __shfl_xor((unsigned int)(v >> 32), xm, 64);
  unsigned int lo = __shfl_xor((unsigned int)(v & 0xFFFFFFFFu), xm, 64);
  unsigned long long o = ((unsigned long long)hi << 32) | lo;
  return (o > v) ? o : v;
}

// One wave per batch. Lane l = (r4 = l>>4, c4 = l&15): owns rows [16r4,16r4+16) x cols [4c4,4c4+4).
// Zero barriers: cross-lane reduce via shfl_xor; alpha handoff via same-wave LDS + lgkmcnt(0).
__global__ __launch_bounds__(64, 1) void viterbi_1w(
    const float* __restrict__ P,
    const int* __restrict__ mask,   // bool input uploaded as int32 (1/0)
    int* __restrict__ out)
{
  __shared__ __align__(16) float ring[DEPTH * T * T];     // 64 KB prefetch ring
  __shared__ __align__(16) float alpha[2][T];             // 512 B, parity double-buffer
  __shared__ __align__(16) unsigned char bp[S * T];       // 32 KB backpointers
  __shared__ __align__(16) int tag_seq[S];                // 2 KB traced tags

  const int l  = threadIdx.x;
  const int c4 = l & 15;
  const int r4 = l >> 4;
  const int b  = blockIdx.x;
  const float* Pb = P + (size_t)b * S * T * T;

  if (r4 == 0) *(float4*)&alpha[0][c4 * 4] = float4{0.f, 0.f, 0.f, 0.f};

  // prologue: DEPTH tiles x 16 x 1KB DMA
  for (int d = 0; d < DEPTH; ++d) {
#pragma unroll
    for (int m = 0; m < 16; ++m)
      load16(Pb + d * 4096 + m * 256 + l * 4, &ring[d * 4096 + m * 256]);
  }
  WAIT_LGKM();   // alpha-init visible wave-wide

  for (int s = 0; s < S; ++s) {
    WAIT_VM48();                    // oldest 16 loads (tile s) landed
    const float* base = &ring[(s & 3) * 4096 + r4 * 1024 + c4 * 4];

    // alpha for my 16 rows (broadcast b128 reads, uniform per 16-lane group)
    float a[16];
#pragma unroll
    for (int q = 0; q < 4; ++q) {
      float4 v = *(const float4*)&alpha[s & 1][r4 * 16 + q * 4];
      a[4*q] = v.x; a[4*q+1] = v.y; a[4*q+2] = v.z; a[4*q+3] = v.w;
    }

    // scan 16 rows x 4 cols; strict > keeps earliest row (first-index ties)
    float best0, best1, best2, best3;
    int bi0 = 0, bi1 = 0, bi2 = 0, bi3 = 0;
    {
      float4 p0 = *(const float4*)(base);
      best0 = a[0] + p0.x; best1 = a[0] + p0.y;
      best2 = a[0] + p0.z; best3 = a[0] + p0.w;
    }
#pragma unroll
    for (int k = 1; k < 16; ++k) {
      float4 pk_ = *(const float4*)(base + k * 64);
      float s0 = a[k] + pk_.x; if (s0 > best0) { best0 = s0; bi0 = k; }
      float s1 = a[k] + pk_.y; if (s1 > best1) { best1 = s1; bi1 = k; }
      float s2 = a[k] + pk_.z; if (s2 > best2) { best2 = s2; bi2 = k; }
      float s3 = a[k] + pk_.w; if (s3 > best3) { best3 = s3; bi3 = k; }
    }

    // pack (score, 255-row) and butterfly over the 4 row-groups (lane bits 4,5)
    const int rbase = r4 * 16;
    unsigned long long k0 = ((unsigned long long)f2s(best0) << 32) | (unsigned)(255 - (rbase + bi0));
    unsigned long long k1 = ((unsigned long long)f2s(best1) << 32) | (unsigned)(255 - (rbase + bi1));
    unsigned long long k2 = ((unsigned long long)f2s(best2) << 32) | (unsigned)(255 - (rbase + bi2));
    unsigned long long k3 = ((unsigned long long)f2s(best3) << 32) | (unsigned)(255 - (rbase + bi3));
    k0 = u64max_x(k0, 16); k0 = u64max_x(k0, 32);
    k1 = u64max_x(k1, 16); k1 = u64max_x(k1, 32);
    k2 = u64max_x(k2, 16); k2 = u64max_x(k2, 32);
    k3 = u64max_x(k3, 16); k3 = u64max_x(k3, 32);

    const int bn0 = 255 - (int)(k0 & 0xFF), bn1 = 255 - (int)(k1 & 0xFF);
    const int bn2 = 255 - (int)(k2 & 0xFF), bn3 = 255 - (int)(k3 & 0xFF);
    if (r4 == 0) {
      *(unsigned int*)&bp[s * 64 + c4 * 4] =
          (unsigned)bn0 | ((unsigned)bn1 << 8) | ((unsigned)bn2 << 16) | ((unsigned)bn3 << 24);
      *(float4*)&alpha[(s + 1) & 1][c4 * 4] =
          float4{s2f((unsigned)(k0 >> 32)), s2f((unsigned)(k1 >> 32)),
                 s2f((unsigned)(k2 >> 32)), s2f((unsigned)(k3 >> 32))};
    }
    WAIT_LGKM();   // my b128 tile reads retired (refill-safe) + alpha/bp visible wave-wide

    // refill consumed slot with tile s+DEPTH (wrap past end -> slot never read again)
    int src = s + DEPTH; if (src >= S) src -= S;
#pragma unroll
    for (int m = 0; m < 16; ++m)
      load16(Pb + src * 4096 + m * 256 + l * 4, &ring[(s & 3) * 4096 + m * 256]);
  }

  // final argmax over tags (max score, tie -> smallest j), full-wave butterfly
  float4 fa = *(const float4*)&alpha[0][c4 * 4];   // S even -> final alpha in buffer 0
  unsigned long long mm = ((unsigned long long)f2s(fa.x) << 32) | (unsigned)(63 - (4 * c4 + 0));
  unsigned long long tt;
  tt = ((unsigned long long)f2s(fa.y) << 32) | (unsigned)(63 - (4 * c4 + 1)); if (tt > mm) mm = tt;
  tt = ((unsigned long long)f2s(fa.z) << 32) | (unsigned)(63 - (4 * c4 + 2)); if (tt > mm) mm = tt;
  tt = ((unsigned long long)f2s(fa.w) << 32) | (unsigned)(63 - (4 * c4 + 3)); if (tt > mm) mm = tt;
  mm = u64max_x(mm, 1); mm = u64max_x(mm, 2); mm = u64max_x(mm, 4);
  mm = u64max_x(mm, 8); mm = u64max_x(mm, 16); mm = u64max_x(mm, 32);
  const int last_tag = 63 - (int)(mm & 0xFF);

  // serial backtrace (latency tail ~25us), tags into LDS
  if (l == 0) {
    int tag = last_tag;
    tag_seq[S - 1] = tag;
    for (int s = S - 1; s >= 1; --s) {
      tag = bp[s * 64 + tag];
      tag_seq[s - 1] = tag;
    }
  }
  WAIT_LGKM();

  // parallel masked output (coalesced)
  const int* mrow = mask + b * S;
  int* orow = out + b * S;
#pragma unroll
  for (int q = 0; q < S / 64; ++q) {
    int s2 = l + q * 64;
    orow[s2] = mrow[s2] ? tag_seq[s2] : -1;
  }

  WAIT_VM0();   // drain wrap-around prefetches before LDS is freed
}

} // namespace

extern "C" void kernel_launch(void* const* d_in, const int* in_sizes, int n_in,
                              void* d_out, int out_size, void* d_ws, size_t ws_size,
                              hipStream_t stream) {
  const float* P = (const float*)d_in[0];
  const int* mask = (const int*)d_in[1];
  int* out = (int*)d_out;
  (void)in_sizes; (void)n_in; (void)out_size; (void)d_ws; (void)ws_size;
  hipLaunchKernelGGL(viterbi_1w, dim3(B), dim3(64), 0, stream, P, mask, out);
}